// Round 6
// baseline (142.129 us; speedup 1.0000x reference)
//
#include <hip/hip_runtime.h>
#include <math.h>

#define SRf 48000.0f
#define CSOUND 343.0f
#define RIR_LEN 24000
#define TAPS 81
#define HALFT 40
#define NB 8
#define NM 21                 // per-axis entries with order <= 10
#define NTRIP (NM * NM * NM)  // 9261 candidate triples
#define CHUNK 3000
#define NCH (RIR_LEN / CHUNK)  // 8 chunks per batch
#define BLOCK 1024
#define MAXIMG 1561            // exact count of kept images per batch (safe cap)

// 0.9^q for q = 0..10
__device__ __constant__ float c_beta[11] = {
    1.0f, 0.9f, 0.81f, 0.729f, 0.6561f, 0.59049f, 0.531441f,
    0.4782969f, 0.43046721f, 0.387420489f, 0.3486784401f};

// Per-axis image table restricted to order <= 10 (pure arithmetic, no LDS):
//   m in [0,10]:  p=0, n=m-5  -> sign=+1, off=2n, order=2|n|
//   m in [11,20]: p=1, n=m-15 -> sign=-1, off=2n, order=|n-1|+|n|
__device__ __forceinline__ void axis_entry(int m, float& sgn, float& off, int& ord) {
    if (m < 11) {
        int n = m - 5;
        sgn = 1.0f;
        off = 2.0f * (float)n;
        ord = 2 * abs(n);
    } else {
        int n = m - 15;
        sgn = -1.0f;
        off = 2.0f * (float)n;
        ord = abs(n - 1) + abs(n);
    }
}

__global__ __launch_bounds__(BLOCK) void rir_kernel(const float* __restrict__ x,
                                                    float* __restrict__ out) {
    __shared__ float s_tile[CHUNK];   // 12 KB
    __shared__ float4 s_e[MAXIMG];    // 25 KB: {amp, frac, sin(pi*frac), i0}
    __shared__ int s_cnt;

    const float PIF = 3.14159265358979323846f;
    const int b = blockIdx.x >> 3;          // / NCH
    const int ch = blockIdx.x & (NCH - 1);
    const int c0 = ch * CHUNK;
    const int tid = threadIdx.x;

    // uniform room params (scalar loads)
    const float* xb = x + b * 9;
    const float r0 = xb[0] * 10.0f, r1 = xb[1] * 10.0f, r2 = xb[2] * 10.0f;
    const float m0 = xb[3] * r0, m1 = xb[4] * r1, m2 = xb[5] * r2;
    const float s0 = xb[6] * r0, s1 = xb[7] * r1, s2 = xb[8] * r2;

    if (tid == 0) s_cnt = 0;
    for (int j = tid; j < CHUNK; j += BLOCK) s_tile[j] = 0.0f;

    if (ch == 0 && tid == 0) {  // fold the 8 origin outputs in
        float d0 = m0 - s0, d1 = m1 - s1, d2 = m2 - s2;
        float dist = sqrtf(d0 * d0 + d1 * d1 + d2 * d2);
        out[NB * RIR_LEN + b] = 40.0f + SRf * dist / CSOUND;
    }
    __syncthreads();

    // ---- phase A: register-only scan of all candidates; compact chunk-hitters
    for (int r = tid; r < NTRIP; r += BLOCK) {
        int mi = r / (NM * NM);
        int rem = r - mi * (NM * NM);
        int mj = rem / NM;
        int mk = rem - mj * NM;

        float si, oi_; int qi; axis_entry(mi, si, oi_, qi);
        float sj, oj_; int qj; axis_entry(mj, sj, oj_, qj);
        float sk, ok_; int qk; axis_entry(mk, sk, ok_, qk);
        int q = qi + qj + qk;
        if (q > 10) continue;

        float dx = si * s0 + oi_ * r0 - m0;
        float dy = sj * s1 + oj_ * r1 - m1;
        float dz = sk * s2 + ok_ * r2 - m2;
        float dist = sqrtf(dx * dx + dy * dy + dz * dz);

        float tau = SRf * dist / CSOUND;
        float i0f = floorf(tau);
        int i0 = (int)i0f;
        // window samples [i0+40, i0+120]; chunk [c0, c0+CHUNK):
        if (i0 < c0 - (HALFT + TAPS - 1) || i0 > c0 + CHUNK - 1 - HALFT) continue;

        float fr = tau - i0f;
        int slot = atomicAdd(&s_cnt, 1);
        float4 e;
        e.x = c_beta[q] / (4.0f * PIF * dist);
        e.y = fr;
        e.z = __sinf(PIF * fr);
        e.w = __int_as_float(i0);
        s_e[slot] = e;
    }
    __syncthreads();

    // ---- phase B: flattened (image, tap) work-items, LDS accumulation
    const int n = s_cnt;
    const int total = n * TAPS;
    for (int w = tid; w < total; w += BLOCK) {
        int img = w / TAPS;
        int ki = w - img * TAPS;
        float4 e = s_e[img];
        int idx = __float_as_int(e.w) + HALFT + ki;
        if (idx < c0 || idx >= c0 + CHUNK) continue;

        float tt = (float)(ki - HALFT) - e.y;
        if (fabsf(tt) > (float)HALFT) continue;

        float win = 0.5f * (1.0f + __cosf(PIF * tt * (1.0f / 41.0f)));
        float snc = (tt == 0.0f) ? 1.0f
                                 : ((ki & 1) ? e.z : -e.z) * __builtin_amdgcn_rcpf(PIF * tt);
        atomicAdd(&s_tile[idx - c0], e.x * snc * win);
    }
    __syncthreads();

    // ---- phase C: disjoint coalesced writeout (covers every output element)
    for (int j = tid; j < CHUNK; j += BLOCK) out[b * RIR_LEN + c0 + j] = s_tile[j];
}

extern "C" void kernel_launch(void* const* d_in, const int* in_sizes, int n_in,
                              void* d_out, int out_size, void* d_ws, size_t ws_size,
                              hipStream_t stream) {
    const float* x = (const float*)d_in[0];
    float* out = (float*)d_out;
    rir_kernel<<<NB * NCH, BLOCK, 0, stream>>>(x, out);
}

// Round 7
// 34.095 us; speedup vs baseline: 4.1686x; 4.1686x over previous
//
#include <hip/hip_runtime.h>
#include <math.h>

#define SRf 48000.0f
#define CSOUND 343.0f
#define RIR_LEN 24000
#define TAPS 81
#define HALFT 40
#define NB 8
#define NM 21                 // per-axis entries with order <= 10
#define NTRIP (NM * NM * NM)  // 9261 candidate triples
#define NSL 8                 // image-slices per batch (r % NSL)
#define BLOCK 1024
#define CAPS 384              // per-slice keeper capacity (true max ~210)

// 0.9^q for q = 0..10
__device__ __constant__ float c_beta[11] = {
    1.0f, 0.9f, 0.81f, 0.729f, 0.6561f, 0.59049f, 0.531441f,
    0.4782969f, 0.43046721f, 0.387420489f, 0.3486784401f};

// Per-axis image table restricted to order <= 10 (pure arithmetic):
//   m in [0,10]:  p=0, n=m-5  -> sign=+1, off=2n, order=2|n|
//   m in [11,20]: p=1, n=m-15 -> sign=-1, off=2n, order=|n-1|+|n|
__device__ __forceinline__ void axis_entry(int m, float& sgn, float& off, int& ord) {
    if (m < 11) {
        int n = m - 5;
        sgn = 1.0f;
        off = 2.0f * (float)n;
        ord = 2 * abs(n);
    } else {
        int n = m - 15;
        sgn = -1.0f;
        off = 2.0f * (float)n;
        ord = abs(n - 1) + abs(n);
    }
}

// kernel 1: block = (batch, slice). Paint the slice's images (r % NSL == slice)
// into a private full-length LDS RIR; stream to d_ws. Work per block is
// input-independent (~195 images, ~16K tap-adds) -> perfectly balanced.
__global__ __launch_bounds__(BLOCK) void k_paint(const float* __restrict__ x,
                                                 float* __restrict__ ws) {
    __shared__ __align__(16) float s_tile[RIR_LEN];  // 96 KB
    __shared__ float4 s_e[CAPS];                     // {amp, frac, sin(pi*frac), i0}
    __shared__ int s_cnt;

    const float PIF = 3.14159265358979323846f;
    const int b = blockIdx.x >> 3;
    const int sl = blockIdx.x & (NSL - 1);
    const int tid = threadIdx.x;

    const float* xb = x + b * 9;
    const float r0 = xb[0] * 10.0f, r1 = xb[1] * 10.0f, r2 = xb[2] * 10.0f;
    const float m0 = xb[3] * r0, m1 = xb[4] * r1, m2 = xb[5] * r2;
    const float s0 = xb[6] * r0, s1 = xb[7] * r1, s2 = xb[8] * r2;

    if (tid == 0) s_cnt = 0;
    for (int j = tid * 4; j < RIR_LEN; j += BLOCK * 4)
        *(float4*)&s_tile[j] = make_float4(0.f, 0.f, 0.f, 0.f);
    __syncthreads();

    // ---- phase A: register-only scan of residue class sl
    for (int base = tid; base * NSL + sl < NTRIP; base += BLOCK) {
        int r = base * NSL + sl;
        int mi = r / (NM * NM);
        int rem = r - mi * (NM * NM);
        int mj = rem / NM;
        int mk = rem - mj * NM;

        float si, oi_; int qi; axis_entry(mi, si, oi_, qi);
        float sj, oj_; int qj; axis_entry(mj, sj, oj_, qj);
        float sk, ok_; int qk; axis_entry(mk, sk, ok_, qk);
        int q = qi + qj + qk;
        if (q > 10) continue;

        float dx = si * s0 + oi_ * r0 - m0;
        float dy = sj * s1 + oj_ * r1 - m1;
        float dz = sk * s2 + ok_ * r2 - m2;
        float dist = sqrtf(dx * dx + dy * dy + dz * dz);

        float tau = SRf * dist / CSOUND;
        float i0f = floorf(tau);
        int i0 = (int)i0f;
        if (i0 + HALFT >= RIR_LEN) continue;  // no taps land in [0, RIR_LEN)

        float fr = tau - i0f;
        int slot = atomicAdd(&s_cnt, 1);
        float4 e;
        e.x = c_beta[q] / (4.0f * PIF * dist);
        e.y = fr;
        e.z = __sinf(PIF * fr);
        e.w = __int_as_float(i0);
        s_e[slot] = e;
    }
    __syncthreads();

    // ---- phase B: flattened (image, tap) items into private LDS RIR
    const int n = s_cnt;
    const int total = n * TAPS;
    for (int w = tid; w < total; w += BLOCK) {
        int img = w / TAPS;
        int ki = w - img * TAPS;
        float4 e = s_e[img];
        int idx = __float_as_int(e.w) + HALFT + ki;
        if (idx >= RIR_LEN) continue;

        float tt = (float)(ki - HALFT) - e.y;
        if (fabsf(tt) > (float)HALFT) continue;

        float win = 0.5f * (1.0f + __cosf(PIF * tt * (1.0f / 41.0f)));
        float snc = (tt == 0.0f) ? 1.0f
                                 : ((ki & 1) ? e.z : -e.z) * __builtin_amdgcn_rcpf(PIF * tt);
        atomicAdd(&s_tile[idx], e.x * snc * win);
    }
    __syncthreads();

    // ---- phase C: stream private RIR to workspace (coalesced float4)
    float* wb = ws + (size_t)(b * NSL + sl) * RIR_LEN;
    for (int j = tid * 4; j < RIR_LEN; j += BLOCK * 4)
        *(float4*)&wb[j] = *(const float4*)&s_tile[j];
}

// kernel 2: sum the NSL partials per batch -> d_out; fold in the 8 origins.
__global__ __launch_bounds__(256) void k_reduce(const float* __restrict__ x,
                                                const float* __restrict__ ws,
                                                float* __restrict__ out) {
    int t4 = (blockIdx.x * 256 + threadIdx.x) * 4;
    if (t4 < NB * RIR_LEN) {
        int b = t4 / RIR_LEN;
        int j = t4 - b * RIR_LEN;
        const float* base = ws + (size_t)b * NSL * RIR_LEN + j;
        float4 acc = *(const float4*)base;
        #pragma unroll
        for (int s = 1; s < NSL; ++s) {
            float4 v = *(const float4*)(base + (size_t)s * RIR_LEN);
            acc.x += v.x; acc.y += v.y; acc.z += v.z; acc.w += v.w;
        }
        *(float4*)(out + t4) = acc;
    }
    if (blockIdx.x == 0 && threadIdx.x < NB) {
        const float* xb = x + threadIdx.x * 9;
        float r0 = xb[0] * 10.0f, r1 = xb[1] * 10.0f, r2 = xb[2] * 10.0f;
        float d0 = (xb[3] - xb[6]) * r0;
        float d1 = (xb[4] - xb[7]) * r1;
        float d2 = (xb[5] - xb[8]) * r2;
        float dist = sqrtf(d0 * d0 + d1 * d1 + d2 * d2);
        out[NB * RIR_LEN + threadIdx.x] = 40.0f + SRf * dist / CSOUND;
    }
}

extern "C" void kernel_launch(void* const* d_in, const int* in_sizes, int n_in,
                              void* d_out, int out_size, void* d_ws, size_t ws_size,
                              hipStream_t stream) {
    const float* x = (const float*)d_in[0];
    float* out = (float*)d_out;
    float* ws = (float*)d_ws;  // NB*NSL*RIR_LEN floats = 6.1 MB

    k_paint<<<NB * NSL, BLOCK, 0, stream>>>(x, ws);
    int rblocks = (NB * RIR_LEN / 4 + 255) / 256;  // 188
    k_reduce<<<rblocks, 256, 0, stream>>>(x, ws, out);
}